// Round 7
// baseline (87.515 us; speedup 1.0000x reference)
//
#include <hip/hip_runtime.h>
#include <math.h>

#define N_ROWS 8192
#define N_NEG 16
#define NBLK (N_ROWS / 8)   // 1024 main-kernel blocks
#define NEG_INF (-3.0e38f)

__device__ __forceinline__ float log_sigmoid(float v) {
    // log(sigmoid(v)) = min(v,0) - log1p(exp(-|v|))  (numerically stable)
    return fminf(v, 0.0f) - log1pf(__expf(-fabsf(v)));
}

__device__ __forceinline__ float wave_max64(float v) {
    v = fmaxf(v, __shfl_xor(v, 1));
    v = fmaxf(v, __shfl_xor(v, 2));
    v = fmaxf(v, __shfl_xor(v, 4));
    v = fmaxf(v, __shfl_xor(v, 8));
    v = fmaxf(v, __shfl_xor(v, 16));
    v = fmaxf(v, __shfl_xor(v, 32));
    return v;
}

// Per-lane sorted-descending top-3 (t0..t2) + watermark t3 = 4th largest.
// Branch-free insert: for sorted t0>=t1>=t2>=t3, med3(c, t_{k-1}, t_k) is
// exactly the sorted-insert shift at slot k. 4 VALU ops, no cross-lane.
#define INS4(cexpr)                                                     \
    {                                                                   \
        const float _c = (cexpr);                                       \
        const float n0 = fmaxf(t0, _c);                                 \
        const float n1 = __builtin_amdgcn_fmed3f(_c, t0, t1);           \
        const float n2 = __builtin_amdgcn_fmed3f(_c, t1, t2);           \
        const float n3 = __builtin_amdgcn_fmed3f(_c, t2, t3);           \
        t0 = n0; t1 = n1; t2 = n2; t3 = n3;                             \
    }

// 8 waves/block, one row per wave. Scan phase: pure VALU, no ballots, no
// shuffles (DS = 32 sel b128 reads only). Merge: 16 wave-max rounds over
// the 64x3 candidates. Exact fallback gated by the t3 watermark.
__global__ __launch_bounds__(512) void nsl_topk_kernel(
        const float* __restrict__ x,
        const int*   __restrict__ sel,
        float*       __restrict__ ws) {
    __shared__ int   sel_lds[N_ROWS];
    __shared__ float partial[8];

    // cooperative stage of the full sel vector (32 KB), coalesced int4
    {
        const int4* s4 = reinterpret_cast<const int4*>(sel);
        int4*       d4 = reinterpret_cast<int4*>(sel_lds);
#pragma unroll
        for (int k = 0; k < 4; ++k)
            d4[k * 512 + threadIdx.x] = s4[k * 512 + threadIdx.x];
    }
    __syncthreads();

    const int lane = threadIdx.x & 63;
    const int wid  = threadIdx.x >> 6;
    const int row  = (blockIdx.x << 3) + wid;

    const int    seli = sel_lds[row];
    const float* xrow = x + (size_t)row * N_ROWS;
    const float* pw   = xrow + (lane << 2);

    float t0 = NEG_INF, t1 = NEG_INF, t2 = NEG_INF, t3 = NEG_INF;

    // chunk c = floats [c*256 .. c*256+255]; lane owns one float4.
#define LOADB(c) (*reinterpret_cast<const float4*>(pw + ((c) << 8)))
#define CONSUME(c, PF)                                                  \
    {                                                                   \
        const float4 v = buf[(c) & 3];                                  \
        if (PF) buf[(c) & 3] = LOADB((c) + 4);                          \
        const int4 s = *reinterpret_cast<const int4*>(                  \
            &sel_lds[((c) << 8) + (lane << 2)]);                        \
        INS4((s.x != seli) ? v.x : 0.0f);                               \
        INS4((s.y != seli) ? v.y : 0.0f);                               \
        INS4((s.z != seli) ? v.z : 0.0f);                               \
        INS4((s.w != seli) ? v.w : 0.0f);                               \
    }

    float4 buf[4];
#pragma unroll
    for (int j = 0; j < 4; ++j) buf[j] = LOADB(j);

#pragma unroll 1
    for (int g = 0; g < 7; ++g) {
        const int c = g << 2;
        CONSUME(c + 0, true);
        CONSUME(c + 1, true);
        CONSUME(c + 2, true);
        CONSUME(c + 3, true);
    }
    CONSUME(28, false);   // tail: no prefetch
    CONSUME(29, false);
    CONSUME(30, false);
    CONSUME(31, false);
#undef CONSUME

    // ---- merge: 16 wave-max selection rounds over 64x3 candidates ----
    const float wmark = t3;        // lane's 4th-largest (never offered)
    float negsum = 0.0f;           // wave-uniform
    float tau = 0.0f;
#pragma unroll 1
    for (int r = 0; r < 16; ++r) {
        const float h = wave_max64(t0);
        negsum += log_sigmoid(-h);
        tau = h;
        const unsigned long long b = __ballot(t0 == h);
        if (lane == (__ffsll(b) - 1)) {       // pop exactly one holder
            t0 = t1; t1 = t2; t2 = NEG_INF;
        }
    }

    // ---- exact fallback: a missed top-16 member implies its lane's
    // watermark >= final tau (candidates subset => tau <= true tau16).
    // P ~ 0.7% of rows: exact distributed-insert rescan.
    if (__any(wmark >= tau)) {
        float dt = NEG_INF, dtau = NEG_INF;   // sorted list in lanes 0..15
#pragma unroll 1
        for (int c = 0; c < 32; ++c) {
            const float4 v = LOADB(c);
            const int4 s = *reinterpret_cast<const int4*>(
                &sel_lds[(c << 8) + (lane << 2)]);
            float m[4];
            m[0] = (s.x != seli) ? v.x : 0.0f;
            m[1] = (s.y != seli) ? v.y : 0.0f;
            m[2] = (s.z != seli) ? v.z : 0.0f;
            m[3] = (s.w != seli) ? v.w : 0.0f;
#pragma unroll
            for (int k = 0; k < 4; ++k) {
                unsigned long long ball = __ballot(m[k] > dtau);
                while (ball) {
                    const int src = __ffsll(ball) - 1;
                    const float cand = __shfl(m[k], src);
                    ball &= ball - 1;
                    if (cand > dtau) {
                        float tprev = __shfl_up(dt, 1);
                        if (lane == 0) tprev = 3.0e38f;
                        dt = (dt >= cand) ? dt : (tprev >= cand ? cand : tprev);
                        dtau = __shfl(dt, 15);
                        ball &= __ballot(m[k] > dtau);
                    }
                }
            }
        }
        float ls = (lane < 16) ? log_sigmoid(-dt) : 0.0f;
        ls += __shfl_xor(ls, 8);
        ls += __shfl_xor(ls, 4);
        ls += __shfl_xor(ls, 2);
        ls += __shfl_xor(ls, 1);
        negsum = ls;               // lane 0's value is the one consumed
    }
#undef LOADB

    if (lane == 0) {
        const float d = xrow[row];              // raw diagonal score
        partial[wid] = -log_sigmoid(d) * (1.0f / (float)N_ROWS)
                       - negsum * (1.0f / ((float)N_ROWS * (float)N_NEG));
    }
    __syncthreads();

    if (threadIdx.x == 0) {
        float s = 0.0f;
#pragma unroll
        for (int w = 0; w < 8; ++w) s += partial[w];
        ws[blockIdx.x] = s;                     // plain store, no atomic
    }
}

// single-block final reduce: 1024 partials -> d_out[0]
__global__ __launch_bounds__(256) void nsl_reduce_kernel(
        const float* __restrict__ ws, float* __restrict__ out) {
    __shared__ float red[4];
    float s = 0.0f;
#pragma unroll
    for (int k = 0; k < NBLK / 256; ++k) s += ws[k * 256 + threadIdx.x];
    s += __shfl_xor(s, 32);
    s += __shfl_xor(s, 16);
    s += __shfl_xor(s, 8);
    s += __shfl_xor(s, 4);
    s += __shfl_xor(s, 2);
    s += __shfl_xor(s, 1);
    const int lane = threadIdx.x & 63, wid = threadIdx.x >> 6;
    if (lane == 0) red[wid] = s;
    __syncthreads();
    if (threadIdx.x == 0)
        out[0] = red[0] + red[1] + red[2] + red[3];
}

extern "C" void kernel_launch(void* const* d_in, const int* in_sizes, int n_in,
                              void* d_out, int out_size, void* d_ws, size_t ws_size,
                              hipStream_t stream) {
    const float* x   = (const float*)d_in[0];
    const int*   sel = (const int*)d_in[1];
    float* out = (float*)d_out;
    float* ws  = (float*)d_ws;

    nsl_topk_kernel<<<dim3(NBLK), dim3(512), 0, stream>>>(x, sel, ws);
    nsl_reduce_kernel<<<dim3(1), dim3(256), 0, stream>>>(ws, out);
}

// Round 8
// 79.551 us; speedup vs baseline: 1.1001x; 1.1001x over previous
//
#include <hip/hip_runtime.h>
#include <math.h>

#define N_ROWS 8192
#define N_NEG 16
#define NBLK (N_ROWS / 8)   // 1024 main-kernel blocks
#define NEG_INF (-3.0e38f)

__device__ __forceinline__ float log_sigmoid(float v) {
    // log(sigmoid(v)) = min(v,0) - log1p(exp(-|v|))  (numerically stable)
    return fminf(v, 0.0f) - log1pf(__expf(-fabsf(v)));
}

// Distributed top-16 insert: lanes 0..15 hold the sorted-descending list.
// cand and tau are wave-uniform.
#define INSERT(mv)                                                          \
    {                                                                       \
        unsigned long long ball = __ballot((mv) > tau);                     \
        while (ball) {                                                      \
            const int src = __ffsll((unsigned long long)ball) - 1;          \
            const float cand = __shfl((mv), src);                           \
            ball &= ball - 1;                                               \
            if (cand > tau) {                                               \
                float tprev = __shfl_up(t, 1);                              \
                if (lane == 0) tprev = 3.0e38f;                             \
                t = (t >= cand) ? t : (tprev >= cand ? cand : tprev);       \
                tau = __shfl(t, 15);                                        \
                ball &= __ballot((mv) > tau); /* prune vs new tau */        \
            }                                                               \
        }                                                                   \
    }

// 8 waves per block, one row per wave. sel staged in LDS. 8-deep register
// prefetch (8 x 1 KB loads in flight per wave). Gated exact top-16 via
// wave-uniform ballot insert. No atomics: per-block partial -> d_ws.
__global__ __launch_bounds__(512) void nsl_topk_kernel(
        const float* __restrict__ x,
        const int*   __restrict__ sel,
        float*       __restrict__ ws) {
    __shared__ int   sel_lds[N_ROWS];
    __shared__ float partial[8];

    // cooperative stage of the full sel vector (32 KB), coalesced int4
    {
        const int4* s4 = reinterpret_cast<const int4*>(sel);
        int4*       d4 = reinterpret_cast<int4*>(sel_lds);
#pragma unroll
        for (int k = 0; k < 4; ++k)
            d4[k * 512 + threadIdx.x] = s4[k * 512 + threadIdx.x];
    }
    __syncthreads();

    const int lane = threadIdx.x & 63;
    const int wid  = threadIdx.x >> 6;
    const int row  = (blockIdx.x << 3) + wid;

    const int    seli = sel_lds[row];
    const float* xrow = x + (size_t)row * N_ROWS;
    const float* pw   = xrow + (lane << 2);

    float t   = NEG_INF;    // this lane's slot of the distributed top-16
    float tau = NEG_INF;    // current 16th-largest (uniform)

    // chunk c = floats [c*256 .. c*256+255]; lane owns one float4. 32 chunks.
#define LOADB(c) (*reinterpret_cast<const float4*>(pw + ((c) << 8)))
#define CONSUME(c, PF)                                                  \
    {                                                                   \
        const float4 v = buf[(c) & 7];                                  \
        if (PF) buf[(c) & 7] = LOADB((c) + 8);                          \
        const float mxv = fmaxf(fmaxf(v.x, v.y), fmaxf(v.z, v.w));      \
        /* exact gate: once tau>=0, raw>tau <=> masked>tau (mask only   \
           writes 0); while tau<0 it fires trivially -> still exact */  \
        if (__any(mxv > tau)) {                                         \
            const int4 s = *reinterpret_cast<const int4*>(              \
                &sel_lds[((c) << 8) + (lane << 2)]);                    \
            const float m0 = (s.x != seli) ? v.x : 0.0f;                \
            const float m1 = (s.y != seli) ? v.y : 0.0f;                \
            const float m2 = (s.z != seli) ? v.z : 0.0f;                \
            const float m3 = (s.w != seli) ? v.w : 0.0f;                \
            INSERT(m0);                                                 \
            INSERT(m1);                                                 \
            INSERT(m2);                                                 \
            INSERT(m3);                                                 \
        }                                                               \
    }

    float4 buf[8];
#pragma unroll
    for (int j = 0; j < 8; ++j) buf[j] = LOADB(j);

#pragma unroll 1
    for (int g = 0; g < 3; ++g) {         // chunks 0..23, prefetch c+8
        const int c = g << 3;
        CONSUME(c + 0, true);
        CONSUME(c + 1, true);
        CONSUME(c + 2, true);
        CONSUME(c + 3, true);
        CONSUME(c + 4, true);
        CONSUME(c + 5, true);
        CONSUME(c + 6, true);
        CONSUME(c + 7, true);
    }
    CONSUME(24, false);                   // tail: chunks 24..31, no prefetch
    CONSUME(25, false);
    CONSUME(26, false);
    CONSUME(27, false);
    CONSUME(28, false);
    CONSUME(29, false);
    CONSUME(30, false);
    CONSUME(31, false);
#undef CONSUME
#undef LOADB

    // negsum over the 16 kept values (lanes 0..15), xor-reduce in-group
    float ls = (lane < 16) ? log_sigmoid(-t) : 0.0f;
    ls += __shfl_xor(ls, 8);
    ls += __shfl_xor(ls, 4);
    ls += __shfl_xor(ls, 2);
    ls += __shfl_xor(ls, 1);

    if (lane == 0) {
        const float d = xrow[row];                      // raw diagonal score
        partial[wid] = -log_sigmoid(d) * (1.0f / (float)N_ROWS)
                       - ls * (1.0f / ((float)N_ROWS * (float)N_NEG));
    }
    __syncthreads();

    if (threadIdx.x == 0) {
        float s = 0.0f;
#pragma unroll
        for (int w = 0; w < 8; ++w) s += partial[w];
        ws[blockIdx.x] = s;                             // plain store, no atomic
    }
}

// single-block final reduce: 1024 partials -> d_out[0]
__global__ __launch_bounds__(256) void nsl_reduce_kernel(
        const float* __restrict__ ws, float* __restrict__ out) {
    __shared__ float red[4];
    float s = 0.0f;
#pragma unroll
    for (int k = 0; k < NBLK / 256; ++k) s += ws[k * 256 + threadIdx.x];
    s += __shfl_xor(s, 32);
    s += __shfl_xor(s, 16);
    s += __shfl_xor(s, 8);
    s += __shfl_xor(s, 4);
    s += __shfl_xor(s, 2);
    s += __shfl_xor(s, 1);
    const int lane = threadIdx.x & 63, wid = threadIdx.x >> 6;
    if (lane == 0) red[wid] = s;
    __syncthreads();
    if (threadIdx.x == 0)
        out[0] = red[0] + red[1] + red[2] + red[3];
}

extern "C" void kernel_launch(void* const* d_in, const int* in_sizes, int n_in,
                              void* d_out, int out_size, void* d_ws, size_t ws_size,
                              hipStream_t stream) {
    const float* x   = (const float*)d_in[0];
    const int*   sel = (const int*)d_in[1];
    float* out = (float*)d_out;
    float* ws  = (float*)d_ws;

    nsl_topk_kernel<<<dim3(NBLK), dim3(512), 0, stream>>>(x, sel, ws);
    nsl_reduce_kernel<<<dim3(1), dim3(256), 0, stream>>>(ws, out);
}

// Round 9
// 57.265 us; speedup vs baseline: 1.5283x; 1.3892x over previous
//
#include <hip/hip_runtime.h>
#include <math.h>

#define N_ROWS 8192
#define N_NEG 16
#define NBLK (N_ROWS / 8)   // 1024 main-kernel blocks
#define NEG_INF (-3.0e38f)
#define TAU0 2.0f           // analytic warm-start threshold (validated per-row)

__device__ __forceinline__ float log_sigmoid(float v) {
    // log(sigmoid(v)) = min(v,0) - log1p(exp(-|v|))  (numerically stable)
    return fminf(v, 0.0f) - log1pf(__expf(-fabsf(v)));
}

__device__ __forceinline__ float bcast_lane(float v, int src) {
    return __int_as_float(__builtin_amdgcn_readlane(__float_as_int(v), src));
}

// Distributed top-16 insert, warm-start variant: lanes 0..15 hold the
// sorted-descending list; tau = max(t[15], TAU0), wave-uniform.
// 1 DS op (shfl_up) per insert; broadcasts via v_readlane.
#define INSERT(mv)                                                          \
    {                                                                       \
        unsigned long long ball = __ballot((mv) > tau);                     \
        while (ball) {                                                      \
            const int src = (int)__ffsll(ball) - 1;                         \
            ball &= ball - 1;                                               \
            const float cand = bcast_lane((mv), src);                       \
            if (cand > tau) {                                               \
                float tprev = __shfl_up(t, 1);                              \
                if (lane == 0) tprev = 3.0e38f;                             \
                t = (t >= cand) ? t : (tprev >= cand ? cand : tprev);       \
                tau = fmaxf(bcast_lane(t, 15), TAU0);                       \
            }                                                               \
        }                                                                   \
    }

// 8 waves per block, one row per wave. sel staged in LDS. 4-deep register
// prefetch. Gated exact top-16 with analytic warm-start + validity check.
__global__ __launch_bounds__(512) void nsl_topk_kernel(
        const float* __restrict__ x,
        const int*   __restrict__ sel,
        float*       __restrict__ ws) {
    __shared__ int   sel_lds[N_ROWS];
    __shared__ float partial[8];

    // cooperative stage of the full sel vector (32 KB), coalesced int4
    {
        const int4* s4 = reinterpret_cast<const int4*>(sel);
        int4*       d4 = reinterpret_cast<int4*>(sel_lds);
#pragma unroll
        for (int k = 0; k < 4; ++k)
            d4[k * 512 + threadIdx.x] = s4[k * 512 + threadIdx.x];
    }
    __syncthreads();

    const int lane = threadIdx.x & 63;
    const int wid  = threadIdx.x >> 6;
    const int row  = (blockIdx.x << 3) + wid;

    const int    seli = sel_lds[row];
    const float* xrow = x + (size_t)row * N_ROWS;
    const float* pw   = xrow + (lane << 2);

    float t   = NEG_INF;    // this lane's slot of the distributed top-16
    float tau = TAU0;       // gate threshold; == TAU0 until 16 entries held

    // chunk c = floats [c*256 .. c*256+255]; lane owns one float4. 32 chunks.
#define LOADB(c) (*reinterpret_cast<const float4*>(pw + ((c) << 8)))
#define CONSUME(c, PF)                                                  \
    {                                                                   \
        const float4 v = buf[(c) & 3];                                  \
        if (PF) buf[(c) & 3] = LOADB((c) + 4);                          \
        const float mxv = fmaxf(fmaxf(v.x, v.y), fmaxf(v.z, v.w));      \
        /* raw-gate is exact: tau >= TAU0 > 0, and mask only writes 0 */\
        if (__any(mxv > tau)) {                                         \
            const int4 s = *reinterpret_cast<const int4*>(              \
                &sel_lds[((c) << 8) + (lane << 2)]);                    \
            const float m0 = (s.x != seli) ? v.x : 0.0f;                \
            const float m1 = (s.y != seli) ? v.y : 0.0f;                \
            const float m2 = (s.z != seli) ? v.z : 0.0f;                \
            const float m3 = (s.w != seli) ? v.w : 0.0f;                \
            INSERT(m0);                                                 \
            INSERT(m1);                                                 \
            INSERT(m2);                                                 \
            INSERT(m3);                                                 \
        }                                                               \
    }

    float4 buf[4];
#pragma unroll
    for (int j = 0; j < 4; ++j) buf[j] = LOADB(j);

#pragma unroll 1
    for (int g = 0; g < 7; ++g) {     // chunks 0..27 with prefetch
        const int c = g << 2;
        CONSUME(c + 0, true);
        CONSUME(c + 1, true);
        CONSUME(c + 2, true);
        CONSUME(c + 3, true);
    }
    CONSUME(28, false);               // tail: no prefetch
    CONSUME(29, false);
    CONSUME(30, false);
    CONSUME(31, false);
#undef CONSUME

    float negsum;
    if (tau > TAU0) {
        // warm-start valid: 16 entries above TAU0 -> exact top-16 in lanes 0..15
        float ls = (lane < 16) ? log_sigmoid(-t) : 0.0f;
        ls += __shfl_xor(ls, 8);
        ls += __shfl_xor(ls, 4);
        ls += __shfl_xor(ls, 2);
        ls += __shfl_xor(ls, 1);
        negsum = ls;
    } else {
        // exact fallback (P ~ 0 for this data): full -inf ballot-insert rescan
        float dt = NEG_INF, dtau = NEG_INF;
#pragma unroll 1
        for (int c = 0; c < 32; ++c) {
            const float4 v = LOADB(c);
            const int4 s = *reinterpret_cast<const int4*>(
                &sel_lds[(c << 8) + (lane << 2)]);
            float m[4];
            m[0] = (s.x != seli) ? v.x : 0.0f;
            m[1] = (s.y != seli) ? v.y : 0.0f;
            m[2] = (s.z != seli) ? v.z : 0.0f;
            m[3] = (s.w != seli) ? v.w : 0.0f;
#pragma unroll
            for (int k = 0; k < 4; ++k) {
                unsigned long long ball = __ballot(m[k] > dtau);
                while (ball) {
                    const int src = (int)__ffsll(ball) - 1;
                    const float cand = __shfl(m[k], src);
                    ball &= ball - 1;
                    if (cand > dtau) {
                        float tprev = __shfl_up(dt, 1);
                        if (lane == 0) tprev = 3.0e38f;
                        dt = (dt >= cand) ? dt : (tprev >= cand ? cand : tprev);
                        dtau = __shfl(dt, 15);
                        ball &= __ballot(m[k] > dtau);
                    }
                }
            }
        }
        float ls = (lane < 16) ? log_sigmoid(-dt) : 0.0f;
        ls += __shfl_xor(ls, 8);
        ls += __shfl_xor(ls, 4);
        ls += __shfl_xor(ls, 2);
        ls += __shfl_xor(ls, 1);
        negsum = ls;
    }
#undef LOADB

    if (lane == 0) {
        const float d = xrow[row];                      // raw diagonal score
        partial[wid] = -log_sigmoid(d) * (1.0f / (float)N_ROWS)
                       - negsum * (1.0f / ((float)N_ROWS * (float)N_NEG));
    }
    __syncthreads();

    if (threadIdx.x == 0) {
        float s = 0.0f;
#pragma unroll
        for (int w = 0; w < 8; ++w) s += partial[w];
        ws[blockIdx.x] = s;                             // plain store, no atomic
    }
}

// single-block final reduce: 1024 partials -> d_out[0]
__global__ __launch_bounds__(256) void nsl_reduce_kernel(
        const float* __restrict__ ws, float* __restrict__ out) {
    __shared__ float red[4];
    float s = 0.0f;
#pragma unroll
    for (int k = 0; k < NBLK / 256; ++k) s += ws[k * 256 + threadIdx.x];
    s += __shfl_xor(s, 32);
    s += __shfl_xor(s, 16);
    s += __shfl_xor(s, 8);
    s += __shfl_xor(s, 4);
    s += __shfl_xor(s, 2);
    s += __shfl_xor(s, 1);
    const int lane = threadIdx.x & 63, wid = threadIdx.x >> 6;
    if (lane == 0) red[wid] = s;
    __syncthreads();
    if (threadIdx.x == 0)
        out[0] = red[0] + red[1] + red[2] + red[3];
}

extern "C" void kernel_launch(void* const* d_in, const int* in_sizes, int n_in,
                              void* d_out, int out_size, void* d_ws, size_t ws_size,
                              hipStream_t stream) {
    const float* x   = (const float*)d_in[0];
    const int*   sel = (const int*)d_in[1];
    float* out = (float*)d_out;
    float* ws  = (float*)d_ws;

    nsl_topk_kernel<<<dim3(NBLK), dim3(512), 0, stream>>>(x, sel, ws);
    nsl_reduce_kernel<<<dim3(1), dim3(256), 0, stream>>>(ws, out);
}

// Round 11
// 56.915 us; speedup vs baseline: 1.5376x; 1.0061x over previous
//
#include <hip/hip_runtime.h>
#include <math.h>

#define N_ROWS 8192
#define N_NEG 16
#define NBLK (N_ROWS / 8)   // 1024 main-kernel blocks
#define NEG_INF (-3.0e38f)
#define TAU0 2.5f           // analytic warm-start threshold (validated per-row)

typedef float  f4 __attribute__((ext_vector_type(4)));
typedef int    i4 __attribute__((ext_vector_type(4)));

__device__ __forceinline__ float log_sigmoid(float v) {
    // log(sigmoid(v)) = min(v,0) - log1p(exp(-|v|))  (numerically stable)
    return fminf(v, 0.0f) - log1pf(__expf(-fabsf(v)));
}

__device__ __forceinline__ float bcast_lane(float v, int src) {
    return __int_as_float(__builtin_amdgcn_readlane(__float_as_int(v), src));
}

// Distributed top-16 insert, warm-start variant: lanes 0..15 hold the
// sorted-descending list; tau = max(t[15], TAU0), wave-uniform.
// 1 DS op (shfl_up) per insert; broadcasts via v_readlane.
#define INSERT(mv)                                                          \
    {                                                                       \
        unsigned long long ball = __ballot((mv) > tau);                     \
        while (ball) {                                                      \
            const int src = (int)__ffsll(ball) - 1;                         \
            ball &= ball - 1;                                               \
            const float cand = bcast_lane((mv), src);                       \
            if (cand > tau) {                                               \
                float tprev = __shfl_up(t, 1);                              \
                if (lane == 0) tprev = 3.0e38f;                             \
                t = (t >= cand) ? t : (tprev >= cand ? cand : tprev);       \
                tau = fmaxf(bcast_lane(t, 15), TAU0);                       \
            }                                                               \
        }                                                                   \
    }

// 8 waves per block, one row per wave. sel read straight from global
// (32 KB -> L1/L2-resident; x loads are nontemporal so they don't evict
// it). No LDS staging, no startup barrier. 4-deep register prefetch.
// Exact top-16 with analytic warm-start + per-row validity check.
__global__ __launch_bounds__(512) void nsl_topk_kernel(
        const float* __restrict__ x,
        const int*   __restrict__ sel,
        float*       __restrict__ ws) {
    __shared__ float partial[8];

    const int lane = threadIdx.x & 63;
    const int wid  = threadIdx.x >> 6;
    const int row  = (blockIdx.x << 3) + wid;

    const int    seli = sel[row];
    const float* xrow = x + (size_t)row * N_ROWS;
    const float* pw   = xrow + (lane << 2);
    const i4*    ps   = reinterpret_cast<const i4*>(sel) + lane;

    float t   = NEG_INF;    // this lane's slot of the distributed top-16
    float tau = TAU0;       // gate threshold; == TAU0 until 16 entries held

    // chunk c = floats [c*256 .. c*256+255]; lane owns one float4. 32 chunks.
#define LOADB(c) __builtin_nontemporal_load(                            \
        reinterpret_cast<const f4*>(pw + ((c) << 8)))
#define CONSUME(c, PF)                                                  \
    {                                                                   \
        const f4 v = buf[(c) & 3];                                      \
        if (PF) buf[(c) & 3] = LOADB((c) + 4);                          \
        const float mxv = fmaxf(fmaxf(v[0], v[1]), fmaxf(v[2], v[3]));  \
        /* raw-gate is exact: tau >= TAU0 > 0, and mask only writes 0 */\
        if (__any(mxv > tau)) {                                         \
            const i4 s = ps[(c) << 6];     /* 64 int4 per chunk */      \
            const float m0 = (s[0] != seli) ? v[0] : 0.0f;              \
            const float m1 = (s[1] != seli) ? v[1] : 0.0f;              \
            const float m2 = (s[2] != seli) ? v[2] : 0.0f;              \
            const float m3 = (s[3] != seli) ? v[3] : 0.0f;              \
            INSERT(m0);                                                 \
            INSERT(m1);                                                 \
            INSERT(m2);                                                 \
            INSERT(m3);                                                 \
        }                                                               \
    }

    f4 buf[4];
#pragma unroll
    for (int j = 0; j < 4; ++j) buf[j] = LOADB(j);

#pragma unroll 1
    for (int g = 0; g < 7; ++g) {     // chunks 0..27 with prefetch
        const int c = g << 2;
        CONSUME(c + 0, true);
        CONSUME(c + 1, true);
        CONSUME(c + 2, true);
        CONSUME(c + 3, true);
    }
    CONSUME(28, false);               // tail: no prefetch
    CONSUME(29, false);
    CONSUME(30, false);
    CONSUME(31, false);
#undef CONSUME

    float negsum;
    if (tau > TAU0) {
        // warm-start valid: 16 entries above TAU0 -> exact top-16 in lanes 0..15
        float ls = (lane < 16) ? log_sigmoid(-t) : 0.0f;
        ls += __shfl_xor(ls, 8);
        ls += __shfl_xor(ls, 4);
        ls += __shfl_xor(ls, 2);
        ls += __shfl_xor(ls, 1);
        negsum = ls;
    } else {
        // exact fallback (P ~ 1e-10 per row): full -inf ballot-insert rescan
        float dt = NEG_INF, dtau = NEG_INF;
#pragma unroll 1
        for (int c = 0; c < 32; ++c) {
            const f4 v = LOADB(c);
            const i4 s = ps[c << 6];
            float m[4];
            m[0] = (s[0] != seli) ? v[0] : 0.0f;
            m[1] = (s[1] != seli) ? v[1] : 0.0f;
            m[2] = (s[2] != seli) ? v[2] : 0.0f;
            m[3] = (s[3] != seli) ? v[3] : 0.0f;
#pragma unroll
            for (int k = 0; k < 4; ++k) {
                unsigned long long ball = __ballot(m[k] > dtau);
                while (ball) {
                    const int src = (int)__ffsll(ball) - 1;
                    const float cand = __shfl(m[k], src);
                    ball &= ball - 1;
                    if (cand > dtau) {
                        float tprev = __shfl_up(dt, 1);
                        if (lane == 0) tprev = 3.0e38f;
                        dt = (dt >= cand) ? dt : (tprev >= cand ? cand : tprev);
                        dtau = __shfl(dt, 15);
                        ball &= __ballot(m[k] > dtau);
                    }
                }
            }
        }
        float ls = (lane < 16) ? log_sigmoid(-dt) : 0.0f;
        ls += __shfl_xor(ls, 8);
        ls += __shfl_xor(ls, 4);
        ls += __shfl_xor(ls, 2);
        ls += __shfl_xor(ls, 1);
        negsum = ls;
    }
#undef LOADB

    if (lane == 0) {
        const float d = xrow[row];                      // raw diagonal score
        partial[wid] = -log_sigmoid(d) * (1.0f / (float)N_ROWS)
                       - negsum * (1.0f / ((float)N_ROWS * (float)N_NEG));
    }
    __syncthreads();

    if (threadIdx.x == 0) {
        float s = 0.0f;
#pragma unroll
        for (int w = 0; w < 8; ++w) s += partial[w];
        ws[blockIdx.x] = s;                             // plain store, no atomic
    }
}

// single-block final reduce: 1024 partials -> d_out[0]
__global__ __launch_bounds__(256) void nsl_reduce_kernel(
        const float* __restrict__ ws, float* __restrict__ out) {
    __shared__ float red[4];
    float s = 0.0f;
#pragma unroll
    for (int k = 0; k < NBLK / 256; ++k) s += ws[k * 256 + threadIdx.x];
    s += __shfl_xor(s, 32);
    s += __shfl_xor(s, 16);
    s += __shfl_xor(s, 8);
    s += __shfl_xor(s, 4);
    s += __shfl_xor(s, 2);
    s += __shfl_xor(s, 1);
    const int lane = threadIdx.x & 63, wid = threadIdx.x >> 6;
    if (lane == 0) red[wid] = s;
    __syncthreads();
    if (threadIdx.x == 0)
        out[0] = red[0] + red[1] + red[2] + red[3];
}

extern "C" void kernel_launch(void* const* d_in, const int* in_sizes, int n_in,
                              void* d_out, int out_size, void* d_ws, size_t ws_size,
                              hipStream_t stream) {
    const float* x   = (const float*)d_in[0];
    const int*   sel = (const int*)d_in[1];
    float* out = (float*)d_out;
    float* ws  = (float*)d_ws;

    nsl_topk_kernel<<<dim3(NBLK), dim3(512), 0, stream>>>(x, sel, ws);
    nsl_reduce_kernel<<<dim3(1), dim3(256), 0, stream>>>(ws, out);
}